// Round 1
// baseline (228643.115 us; speedup 1.0000x reference)
//
#include <hip/hip_runtime.h>
#include <hip/hip_cooperative_groups.h>

namespace cg = cooperative_groups;

#define Bn 128
#define Tn 1024
#define INn 256
#define Hn 512

__device__ __forceinline__ float sigm(float x) { return 1.0f / (1.0f + __expf(-x)); }

// two dot products sharing the x stream (two gate rows)
__device__ __forceinline__ void dot2(const float* __restrict__ x,
                                     const float* __restrict__ wa,
                                     const float* __restrict__ wb,
                                     int K, float& a0, float& a1) {
#pragma unroll 4
  for (int k = 0; k < K; k += 4) {
    const float4 xv = *reinterpret_cast<const float4*>(x + k);
    const float4 ua = *reinterpret_cast<const float4*>(wa + k);
    const float4 ub = *reinterpret_cast<const float4*>(wb + k);
    a0 = fmaf(ua.x, xv.x, a0); a0 = fmaf(ua.y, xv.y, a0);
    a0 = fmaf(ua.z, xv.z, a0); a0 = fmaf(ua.w, xv.w, a0);
    a1 = fmaf(ub.x, xv.x, a1); a1 = fmaf(ub.y, xv.y, a1);
    a1 = fmaf(ub.z, xv.z, a1); a1 = fmaf(ub.w, xv.w, a1);
  }
}

// Persistent 3-layer LSTM. 512 blocks x 256 threads, cooperative.
// Block j owns hidden unit j of every layer. Thread = (gsel, b):
//   gsel 0 computes gates (i, f), gsel 1 computes (g, o); exchange via LDS.
// Phase p runs layer1@t=p, layer2@t=p-1, layer3@t=p-2 (software pipeline),
// so a single grid.sync per phase is sufficient.
__global__ __launch_bounds__(256, 2) void lstm_persist(
    const float* __restrict__ embed,
    const float* __restrict__ wih1, const float* __restrict__ whh1,
    const float* __restrict__ bih1, const float* __restrict__ bhh1,
    const float* __restrict__ wih2, const float* __restrict__ whh2,
    const float* __restrict__ bih2, const float* __restrict__ bhh2,
    const float* __restrict__ wih3, const float* __restrict__ whh3,
    const float* __restrict__ bih3, const float* __restrict__ bhh3,
    const float* __restrict__ fcw, const float* __restrict__ fcb,
    float* __restrict__ hws, float* __restrict__ out)
{
  const int j = blockIdx.x;            // 0..511
  const int tid = (int)threadIdx.x;    // 0..255
  const int b = tid & (Bn - 1);
  const int gsel = tid >> 7;           // 0: (i,f)  1: (g,o)

  float* H1 = hws;                     // [2][Bn][Hn]
  float* H2 = hws + 2 * Bn * Hn;
  float* H3 = hws + 4 * Bn * Hn;

  __shared__ float sg[3][Bn];
  __shared__ float so[3][Bn];

  // gate rows (wave-uniform: one gsel per wave); force SGPR for scalar loads
  int r0 = (gsel == 0) ? j : (2 * Hn + j);
  int r1 = (gsel == 0) ? (Hn + j) : (3 * Hn + j);
  r0 = __builtin_amdgcn_readfirstlane(r0);
  r1 = __builtin_amdgcn_readfirstlane(r1);

  const float* wx1a = wih1 + (size_t)r0 * INn;
  const float* wx1b = wih1 + (size_t)r1 * INn;
  const float* wh1a = whh1 + (size_t)r0 * Hn;
  const float* wh1b = whh1 + (size_t)r1 * Hn;
  const float* wx2a = wih2 + (size_t)r0 * Hn;
  const float* wx2b = wih2 + (size_t)r1 * Hn;
  const float* wh2a = whh2 + (size_t)r0 * Hn;
  const float* wh2b = whh2 + (size_t)r1 * Hn;
  const float* wx3a = wih3 + (size_t)r0 * Hn;
  const float* wx3b = wih3 + (size_t)r1 * Hn;
  const float* wh3a = whh3 + (size_t)r0 * Hn;
  const float* wh3b = whh3 + (size_t)r1 * Hn;

  const float bsA1 = bih1[r0] + bhh1[r0];
  const float bsB1 = bih1[r1] + bhh1[r1];
  const float bsA2 = bih2[r0] + bhh2[r0];
  const float bsB2 = bih2[r1] + bhh2[r1];
  const float bsA3 = bih3[r0] + bhh3[r0];
  const float bsB3 = bih3[r1] + bhh3[r1];

  // zero all h double-buffers (deterministic across calls)
  for (int i = blockIdx.x * 256 + tid; i < 6 * Bn * Hn; i += 512 * 256)
    hws[i] = 0.0f;

  float c1 = 0.0f, c2 = 0.0f, c3 = 0.0f;

  cg::grid_group grid = cg::this_grid();
  grid.sync();

  for (int p = 0; p <= Tn; ++p) {
    const int cur = p & 1;
    const int nxt = cur ^ 1;
    const float* h1c = H1 + cur * Bn * Hn;
    const float* h2c = H2 + cur * Bn * Hn;
    const float* h3c = H3 + cur * Bn * Hn;

    const bool a1 = (p <= Tn - 2);               // t1 = p       in [0,1022]
    const bool a2 = (p >= 1) && (p <= Tn - 1);   // t2 = p-1
    const bool a3 = (p >= 2);                    // t3 = p-2

    float A1a = 0.0f, A1b = 0.0f, A2a = 0.0f, A2b = 0.0f, A3a = 0.0f, A3b = 0.0f;

    if (a1) {
      A1a = bsA1; A1b = bsB1;
      dot2(embed + ((size_t)b * Tn + p) * INn, wx1a, wx1b, INn, A1a, A1b);
      dot2(h1c + (size_t)b * Hn, wh1a, wh1b, Hn, A1a, A1b);
    }
    if (a2) {
      A2a = bsA2; A2b = bsB2;
      dot2(h1c + (size_t)b * Hn, wx2a, wx2b, Hn, A2a, A2b);
      dot2(h2c + (size_t)b * Hn, wh2a, wh2b, Hn, A2a, A2b);
    }
    if (a3) {
      A3a = bsA3; A3b = bsB3;
      dot2(h2c + (size_t)b * Hn, wx3a, wx3b, Hn, A3a, A3b);
      dot2(h3c + (size_t)b * Hn, wh3a, wh3b, Hn, A3a, A3b);
    }

    if (gsel == 1) {              // publish (g, o) pre-activations
      sg[0][b] = A1a; so[0][b] = A1b;
      sg[1][b] = A2a; so[1][b] = A2b;
      sg[2][b] = A3a; so[2][b] = A3b;
    }
    __syncthreads();
    if (gsel == 0) {              // cell update; c stays in registers
      if (a1) {
        const float ig = sigm(A1a), fg = sigm(A1b);
        const float gg = tanhf(sg[0][b]), og = sigm(so[0][b]);
        c1 = fg * c1 + ig * gg;
        (H1 + nxt * Bn * Hn)[(size_t)b * Hn + j] = og * tanhf(c1);
      }
      if (a2) {
        const float ig = sigm(A2a), fg = sigm(A2b);
        const float gg = tanhf(sg[1][b]), og = sigm(so[1][b]);
        c2 = fg * c2 + ig * gg;
        (H2 + nxt * Bn * Hn)[(size_t)b * Hn + j] = og * tanhf(c2);
      }
      if (a3) {
        const float ig = sigm(A3a), fg = sigm(A3b);
        const float gg = tanhf(sg[2][b]), og = sigm(so[2][b]);
        c3 = fg * c3 + ig * gg;
        (H3 + nxt * Bn * Hn)[(size_t)b * Hn + j] = og * tanhf(c3);
      }
    }
    grid.sync();
  }

  // FC epilogue: out2[b][o] = h3_final[b,:] . fc_w[o,:] + fc_b[o]
  const float* h3f = H3 + 1 * Bn * Hn;   // final write at p=1024 went to parity 1
  const int gid = blockIdx.x * 256 + tid;
  if (gid < Bn * INn) {
    const int bb = gid >> 8;
    const int oo = gid & (INn - 1);
    float acc = fcb[oo];
    const float* hr = h3f + (size_t)bb * Hn;
    const float* wr = fcw + (size_t)oo * Hn;
#pragma unroll 4
    for (int k = 0; k < Hn; k += 4) {
      const float4 hv = *reinterpret_cast<const float4*>(hr + k);
      const float4 wv = *reinterpret_cast<const float4*>(wr + k);
      acc = fmaf(hv.x, wv.x, acc); acc = fmaf(hv.y, wv.y, acc);
      acc = fmaf(hv.z, wv.z, acc); acc = fmaf(hv.w, wv.w, acc);
    }
    out[(size_t)Bn * Tn * INn + gid] = acc;
  }
}

extern "C" void kernel_launch(void* const* d_in, const int* in_sizes, int n_in,
                              void* d_out, int out_size, void* d_ws, size_t ws_size,
                              hipStream_t stream) {
  const float* embed = (const float*)d_in[0];
  const float* wih1  = (const float*)d_in[1];
  const float* whh1  = (const float*)d_in[2];
  const float* bih1  = (const float*)d_in[3];
  const float* bhh1  = (const float*)d_in[4];
  const float* wih2  = (const float*)d_in[5];
  const float* whh2  = (const float*)d_in[6];
  const float* bih2  = (const float*)d_in[7];
  const float* bhh2  = (const float*)d_in[8];
  const float* wih3  = (const float*)d_in[9];
  const float* whh3  = (const float*)d_in[10];
  const float* bih3  = (const float*)d_in[11];
  const float* bhh3  = (const float*)d_in[12];
  const float* fcw   = (const float*)d_in[13];
  const float* fcb   = (const float*)d_in[14];
  float* outp = (float*)d_out;
  float* hws  = (float*)d_ws;

  // Output 0: embed passthrough (128 MB d2d copy)
  hipMemcpyAsync(d_out, d_in[0], (size_t)Bn * Tn * INn * sizeof(float),
                 hipMemcpyDeviceToDevice, stream);

  void* args[] = { (void*)&embed,
                   (void*)&wih1, (void*)&whh1, (void*)&bih1, (void*)&bhh1,
                   (void*)&wih2, (void*)&whh2, (void*)&bih2, (void*)&bhh2,
                   (void*)&wih3, (void*)&whh3, (void*)&bih3, (void*)&bhh3,
                   (void*)&fcw, (void*)&fcb,
                   (void*)&hws, (void*)&outp };
  dim3 grid(512), block(256);
  hipLaunchCooperativeKernel((const void*)lstm_persist, grid, block, args, 0, stream);
}

// Round 2
// 74578.204 us; speedup vs baseline: 3.0658x; 3.0658x over previous
//
#include <hip/hip_runtime.h>
#include <hip/hip_cooperative_groups.h>

namespace cg = cooperative_groups;

#define Bn 128
#define Tn 1024
#define INn 256
#define Hn 512

typedef short bf16x8 __attribute__((ext_vector_type(8)));
typedef float f32x4 __attribute__((ext_vector_type(4)));

// ---- ws layout (bytes) ----
// Whi  bf16 [5767168]   @ 0
// Wlo  bf16 [5767168]   @ 11534336
// bias f32  [3][2048]   @ 23068672
// hhi  bf16 [3][2][128][512] @ 23093248
// hlo  bf16 [3][2][128][512] @ 23879680
// h3f  f32  [2][128][512]    @ 24666112   (total ~25.2 MB)
#define WHI_OFF  0
#define WLO_OFF  11534336u
#define BIAS_OFF 23068672u
#define HHI_OFF  23093248u
#define HLO_OFF  23879680u
#define H3F_OFF  24666112u

__device__ __forceinline__ float sigm(float x) { return 1.0f / (1.0f + __expf(-x)); }
__device__ __forceinline__ unsigned short bf_hi(float x) {
  unsigned u = __builtin_bit_cast(unsigned, x);
  return (unsigned short)(u >> 16);
}
__device__ __forceinline__ float bf_f(unsigned short h) {
  unsigned u = ((unsigned)h) << 16;
  return __builtin_bit_cast(float, u);
}

// Pack fp32 weights into MFMA-fragment-ordered bf16 hi/lo arrays.
// One thread per (l, jt, ns, kc, lane) producing 8 contiguous-k elems.
// dst elem offset = layer_base + (((jt*2+ns)*NCH + kc)*64 + lane)*8
__global__ void pack_weights(const float* __restrict__ wih1, const float* __restrict__ whh1,
                             const float* __restrict__ wih2, const float* __restrict__ whh2,
                             const float* __restrict__ wih3, const float* __restrict__ whh3,
                             unsigned short* __restrict__ whi, unsigned short* __restrict__ wlo) {
  int gid = blockIdx.x * 256 + threadIdx.x;
  int rem, NCH, kih; size_t base; const float *wih, *whh;
  if (gid < 196608)      { rem = gid;          base = 0;       NCH = 24; kih = 256; wih = wih1; whh = whh1; }
  else if (gid < 458752) { rem = gid - 196608; base = 1572864; NCH = 32; kih = 512; wih = wih2; whh = whh2; }
  else if (gid < 720896) { rem = gid - 458752; base = 3670016; NCH = 32; kih = 512; wih = wih3; whh = whh3; }
  else return;
  const int lane = rem & 63; rem >>= 6;
  const int kc = rem % NCH; rem /= NCH;
  const int ns = rem & 1;
  const int jt = rem >> 1;
  const int n = ns * 16 + (lane & 15);
  const int g = n >> 3, jl = n & 7;
  const int r = g * 512 + jt * 8 + jl;
  const int k0 = kc * 32 + (lane >> 4) * 8;
  const float* src = (k0 < kih) ? (wih + (size_t)r * kih + k0)
                                : (whh + (size_t)r * 512 + (k0 - kih));
  size_t dst = base + ((((size_t)jt * 2 + ns) * NCH + kc) * 64 + lane) * 8;
#pragma unroll
  for (int e = 0; e < 8; ++e) {
    float w = src[e];
    unsigned short h = bf_hi(w);
    whi[dst + e] = h;
    wlo[dst + e] = bf_hi(w - bf_f(h));
  }
}

__global__ void pack_bias(const float* __restrict__ bi1, const float* __restrict__ bh1,
                          const float* __restrict__ bi2, const float* __restrict__ bh2,
                          const float* __restrict__ bi3, const float* __restrict__ bh3,
                          float* __restrict__ bias) {
  int gid = blockIdx.x * 256 + threadIdx.x;
  if (gid >= 6144) return;
  int l = gid >> 11, r = gid & 2047;
  const float* bi = (l == 0) ? bi1 : (l == 1) ? bi2 : bi3;
  const float* bh = (l == 0) ? bh1 : (l == 1) ? bh2 : bh3;
  bias[gid] = bi[r] + bh[r];
}

// Persistent MFMA LSTM. 384 blocks x 256 threads (cooperative).
// Block = (layer l, b-tile of 64, j-tile of 8). Gate tile [64 b x 32 rows],
// rows = 4 gates x 8 j. 4 waves: wave w owns b-rows [w*16, w*16+16), both
// 16-col n-subtiles. Split-bf16: preact = Whi*xhi + Whi*xlo + Wlo*xhi.
// Software pipeline layer l at t = p - l; one grid.sync per phase.
__global__ __launch_bounds__(256, 2) void lstm_mfma(
    const float* __restrict__ embed,
    const unsigned short* __restrict__ whi,
    const unsigned short* __restrict__ wlo,
    const float* __restrict__ bias,
    unsigned short* __restrict__ hhi,
    unsigned short* __restrict__ hlo,
    float* __restrict__ h3f,
    const float* __restrict__ fcw, const float* __restrict__ fcb,
    float* __restrict__ out)
{
  const int bid = blockIdx.x;
  const int l  = bid >> 7;           // 128 blocks per layer
  const int tix = bid & 127;
  const int b0 = (tix >> 6) * 64;    // b-tile base
  const int jt = tix & 63;           // j-tile
  const int j0 = jt * 8;
  const int tid = (int)threadIdx.x;
  const int wave = tid >> 6, lane = tid & 63;
  const int K   = (l == 0) ? 768 : 1024;
  const int NCH = K >> 5;            // 32-k chunks
  const size_t wbase = (l == 0) ? 0 : ((l == 1) ? 1572864 : 3670016);

  __shared__ short lx_hi[2][64][40];  // padded: row stride 80B -> 2-way banks
  __shared__ short lx_lo[2][64][40];
  __shared__ float pre[64][33];
  __shared__ float sbias[32];

  if (tid < 32) {
    int g = tid >> 3, jl = tid & 7;
    sbias[tid] = bias[l * 2048 + g * 512 + j0 + jl];
  }
  // zero h state (poisoned ws; deterministic every call)
  for (int i = bid * 256 + tid; i < 3 * 2 * Bn * Hn; i += 384 * 256) { hhi[i] = 0; hlo[i] = 0; }
  for (int i = bid * 256 + tid; i < 2 * Bn * Hn; i += 384 * 256) h3f[i] = 0.0f;

  float c0 = 0.0f, c1 = 0.0f;
  cg::grid_group grid = cg::this_grid();
  grid.sync();

  const int srow = tid >> 2;         // staging: b-local row 0..63
  const int sc8  = (tid & 3) * 8;    // k-offset within 32-chunk
  const int sb   = b0 + srow;

  for (int p = 0; p <= 1024; ++p) {
    const int t = p - l;
    const bool act = (t >= 0) && (t <= 1022);
    const int rp = (p + 1) & 1, wp = p & 1;

    if (act) {
      f32x4 acc0 = {0.f, 0.f, 0.f, 0.f}, acc1 = {0.f, 0.f, 0.f, 0.f};

      auto stage = [&](int kc, int tobuf) {
        const int gk = kc * 32 + sc8;
        bf16x8 vhi, vlo;
        if (l == 0 && gk < 256) {
          const float* s = embed + ((size_t)sb * Tn + t) * INn + gk;
          const float4 x0 = *reinterpret_cast<const float4*>(s);
          const float4 x1 = *reinterpret_cast<const float4*>(s + 4);
          float xs0[4] = {x0.x, x0.y, x0.z, x0.w};
          float xs1[4] = {x1.x, x1.y, x1.z, x1.w};
#pragma unroll
          for (int e = 0; e < 4; ++e) {
            unsigned short h = bf_hi(xs0[e]);
            vhi[e] = (short)h; vlo[e] = (short)bf_hi(xs0[e] - bf_f(h));
          }
#pragma unroll
          for (int e = 0; e < 4; ++e) {
            unsigned short h = bf_hi(xs1[e]);
            vhi[4 + e] = (short)h; vlo[4 + e] = (short)bf_hi(xs1[e] - bf_f(h));
          }
        } else {
          int srcl, off;
          if (l == 0)            { srcl = 0;     off = gk - 256; }
          else if (gk < 512)     { srcl = l - 1; off = gk;       }
          else                   { srcl = l;     off = gk - 512; }
          const size_t ho = (((size_t)srcl * 2 + rp) * Bn + sb) * Hn + off;
          vhi = *reinterpret_cast<const bf16x8*>(hhi + ho);
          vlo = *reinterpret_cast<const bf16x8*>(hlo + ho);
        }
        *reinterpret_cast<bf16x8*>(&lx_hi[tobuf][srow][sc8]) = vhi;
        *reinterpret_cast<bf16x8*>(&lx_lo[tobuf][srow][sc8]) = vlo;
      };

      int buf = 0;
      stage(0, 0);
      const int ar = wave * 16 + (lane & 15);
      const int ak = (lane >> 4) * 8;
      for (int kc = 0; kc < NCH; ++kc) {
        __syncthreads();
        if (kc + 1 < NCH) stage(kc + 1, buf ^ 1);
        const bf16x8 ahi = *reinterpret_cast<const bf16x8*>(&lx_hi[buf][ar][ak]);
        const bf16x8 alo = *reinterpret_cast<const bf16x8*>(&lx_lo[buf][ar][ak]);
        const size_t o0 = wbase + (((size_t)jt * 2 + 0) * NCH + kc) * 512 + lane * 8;
        const size_t o1 = wbase + (((size_t)jt * 2 + 1) * NCH + kc) * 512 + lane * 8;
        const bf16x8 bh0 = *reinterpret_cast<const bf16x8*>(whi + o0);
        const bf16x8 bh1 = *reinterpret_cast<const bf16x8*>(whi + o1);
        const bf16x8 bl0 = *reinterpret_cast<const bf16x8*>(wlo + o0);
        const bf16x8 bl1 = *reinterpret_cast<const bf16x8*>(wlo + o1);
        acc0 = __builtin_amdgcn_mfma_f32_16x16x32_bf16(ahi, bh0, acc0, 0, 0, 0);
        acc0 = __builtin_amdgcn_mfma_f32_16x16x32_bf16(alo, bh0, acc0, 0, 0, 0);
        acc0 = __builtin_amdgcn_mfma_f32_16x16x32_bf16(ahi, bl0, acc0, 0, 0, 0);
        acc1 = __builtin_amdgcn_mfma_f32_16x16x32_bf16(ahi, bh1, acc1, 0, 0, 0);
        acc1 = __builtin_amdgcn_mfma_f32_16x16x32_bf16(alo, bh1, acc1, 0, 0, 0);
        acc1 = __builtin_amdgcn_mfma_f32_16x16x32_bf16(ahi, bl1, acc1, 0, 0, 0);
        buf ^= 1;
      }
      // C/D layout (m89-verified): col = lane&15, row_b = (lane>>4)*4 + reg
      {
        const int prow = wave * 16 + ((lane >> 4) << 2);
        const int pc = lane & 15;
#pragma unroll
        for (int r2 = 0; r2 < 4; ++r2) {
          pre[prow + r2][pc] = acc0[r2];
          pre[prow + r2][16 + pc] = acc1[r2];
        }
      }
      __syncthreads();
      // cell update: thread -> (bloc = tid>>2, 2 adjacent j)
      {
        const int bloc = tid >> 2;
        const int jb = (tid & 3) * 2;
        float hv0, hv1;
        {
          const int n = jb;
          const float ig = sigm(pre[bloc][n]      + sbias[n]);
          const float fg = sigm(pre[bloc][8 + n]  + sbias[8 + n]);
          const float gg = tanhf(pre[bloc][16 + n] + sbias[16 + n]);
          const float og = sigm(pre[bloc][24 + n] + sbias[24 + n]);
          c0 = fg * c0 + ig * gg;
          hv0 = og * tanhf(c0);
        }
        {
          const int n = jb + 1;
          const float ig = sigm(pre[bloc][n]      + sbias[n]);
          const float fg = sigm(pre[bloc][8 + n]  + sbias[8 + n]);
          const float gg = tanhf(pre[bloc][16 + n] + sbias[16 + n]);
          const float og = sigm(pre[bloc][24 + n] + sbias[24 + n]);
          c1 = fg * c1 + ig * gg;
          hv1 = og * tanhf(c1);
        }
        const size_t ho = (((size_t)l * 2 + wp) * Bn + (b0 + bloc)) * Hn + (j0 + jb);
        const unsigned short h0 = bf_hi(hv0), h1 = bf_hi(hv1);
        hhi[ho] = h0;     hhi[ho + 1] = h1;
        hlo[ho] = bf_hi(hv0 - bf_f(h0));
        hlo[ho + 1] = bf_hi(hv1 - bf_f(h1));
        if (l == 2) {
          const size_t go = ((size_t)wp * Bn + (b0 + bloc)) * Hn + (j0 + jb);
          h3f[go] = hv0; h3f[go + 1] = hv1;
        }
      }
    }
    grid.sync();
  }

  // FC epilogue: final h3 was written at p=1024 (wp=0)
  const int gid = bid * 256 + tid;
  if (gid < Bn * INn) {
    const int b = gid >> 8, o = gid & 255;
    const float* hr = h3f + (size_t)b * Hn;
    const float* wr = fcw + (size_t)o * Hn;
    float acc = fcb[o];
#pragma unroll 4
    for (int k = 0; k < Hn; k += 4) {
      const float4 hv = *reinterpret_cast<const float4*>(hr + k);
      const float4 wv = *reinterpret_cast<const float4*>(wr + k);
      acc = fmaf(hv.x, wv.x, acc); acc = fmaf(hv.y, wv.y, acc);
      acc = fmaf(hv.z, wv.z, acc); acc = fmaf(hv.w, wv.w, acc);
    }
    out[(size_t)Bn * Tn * INn + gid] = acc;
  }
}

extern "C" void kernel_launch(void* const* d_in, const int* in_sizes, int n_in,
                              void* d_out, int out_size, void* d_ws, size_t ws_size,
                              hipStream_t stream) {
  const float* embed = (const float*)d_in[0];
  const float* wih1  = (const float*)d_in[1];
  const float* whh1  = (const float*)d_in[2];
  const float* bih1  = (const float*)d_in[3];
  const float* bhh1  = (const float*)d_in[4];
  const float* wih2  = (const float*)d_in[5];
  const float* whh2  = (const float*)d_in[6];
  const float* bih2  = (const float*)d_in[7];
  const float* bhh2  = (const float*)d_in[8];
  const float* wih3  = (const float*)d_in[9];
  const float* whh3  = (const float*)d_in[10];
  const float* bih3  = (const float*)d_in[11];
  const float* bhh3  = (const float*)d_in[12];
  const float* fcw   = (const float*)d_in[13];
  const float* fcb   = (const float*)d_in[14];
  float* outp = (float*)d_out;

  char* ws = (char*)d_ws;
  unsigned short* whi = (unsigned short*)(ws + WHI_OFF);
  unsigned short* wlo = (unsigned short*)(ws + WLO_OFF);
  float* bias         = (float*)(ws + BIAS_OFF);
  unsigned short* hhi = (unsigned short*)(ws + HHI_OFF);
  unsigned short* hlo = (unsigned short*)(ws + HLO_OFF);
  float* h3f          = (float*)(ws + H3F_OFF);

  // Output 0: embed passthrough (128 MB d2d)
  hipMemcpyAsync(d_out, d_in[0], (size_t)Bn * Tn * INn * sizeof(float),
                 hipMemcpyDeviceToDevice, stream);

  pack_weights<<<2816, 256, 0, stream>>>(wih1, whh1, wih2, whh2, wih3, whh3, whi, wlo);
  pack_bias<<<24, 256, 0, stream>>>(bih1, bhh1, bih2, bhh2, bih3, bhh3, bias);

  void* args[] = { (void*)&embed, (void*)&whi, (void*)&wlo, (void*)&bias,
                   (void*)&hhi, (void*)&hlo, (void*)&h3f,
                   (void*)&fcw, (void*)&fcb, (void*)&outp };
  dim3 grid(384), block(256);
  hipLaunchCooperativeKernel((const void*)lstm_mfma, grid, block, args, 0, stream);
}

// Round 3
// 62171.320 us; speedup vs baseline: 3.6776x; 1.1996x over previous
//
#include <hip/hip_runtime.h>

#define Bn 128
#define Tn 1024
#define INn 256
#define Hn 512
#define NB 256   // grid blocks (1 per CU)

typedef short bf16x8 __attribute__((ext_vector_type(8)));
typedef float f32x4 __attribute__((ext_vector_type(4)));

// ---- ws layout (bytes) ----
#define WHI_OFF  0u
#define WLO_OFF  11534336u
#define BIAS_OFF 23068672u
#define HHI_OFF  23093248u
#define HLO_OFF  23879680u
#define H3F_OFF  24666112u
#define CNT_OFF  24928256u

__device__ __forceinline__ float sigm(float x) { return 1.0f / (1.0f + __expf(-x)); }
__device__ __forceinline__ unsigned short bf_hi(float x) {
  unsigned u = __builtin_bit_cast(unsigned, x);
  return (unsigned short)(u >> 16);
}
__device__ __forceinline__ float bf_f(unsigned short h) {
  unsigned u = ((unsigned)h) << 16;
  return __builtin_bit_cast(float, u);
}

// Pack fp32 weights into MFMA-fragment-ordered bf16 hi/lo arrays (as round 2).
// dst elem offset = layer_base + (((jt*2+ns)*NCH + kc)*64 + lane)*8
// fragment: col n = ns*16 + (lane&15) -> gate row r = (n>>3)*512 + jt*8 + (n&7),
//           k0 = kc*32 + (lane>>4)*8 over concat [x ; h].
__global__ void pack_weights(const float* __restrict__ wih1, const float* __restrict__ whh1,
                             const float* __restrict__ wih2, const float* __restrict__ whh2,
                             const float* __restrict__ wih3, const float* __restrict__ whh3,
                             unsigned short* __restrict__ whi, unsigned short* __restrict__ wlo) {
  int gid = blockIdx.x * 256 + threadIdx.x;
  int rem, NCH, kih; size_t base; const float *wih, *whh;
  if (gid < 196608)      { rem = gid;          base = 0;       NCH = 24; kih = 256; wih = wih1; whh = whh1; }
  else if (gid < 458752) { rem = gid - 196608; base = 1572864; NCH = 32; kih = 512; wih = wih2; whh = whh2; }
  else if (gid < 720896) { rem = gid - 458752; base = 3670016; NCH = 32; kih = 512; wih = wih3; whh = whh3; }
  else return;
  const int lane = rem & 63; rem >>= 6;
  const int kc = rem % NCH; rem /= NCH;
  const int ns = rem & 1;
  const int jt = rem >> 1;
  const int n = ns * 16 + (lane & 15);
  const int g = n >> 3, jl = n & 7;
  const int r = g * 512 + jt * 8 + jl;
  const int k0 = kc * 32 + (lane >> 4) * 8;
  const float* src = (k0 < kih) ? (wih + (size_t)r * kih + k0)
                                : (whh + (size_t)r * 512 + (k0 - kih));
  size_t dst = base + ((((size_t)jt * 2 + ns) * NCH + kc) * 64 + lane) * 8;
#pragma unroll
  for (int e = 0; e < 8; ++e) {
    float w = src[e];
    unsigned short h = bf_hi(w);
    whi[dst + e] = h;
    wlo[dst + e] = bf_hi(w - bf_f(h));
  }
}

__global__ void pack_bias(const float* __restrict__ bi1, const float* __restrict__ bh1,
                          const float* __restrict__ bi2, const float* __restrict__ bh2,
                          const float* __restrict__ bi3, const float* __restrict__ bh3,
                          float* __restrict__ bias) {
  int gid = blockIdx.x * 256 + threadIdx.x;
  if (gid >= 6144) return;
  int l = gid >> 11, r = gid & 2047;
  const float* bi = (l == 0) ? bi1 : (l == 1) ? bi2 : bi3;
  const float* bh = (l == 0) ? bh1 : (l == 1) ? bh2 : bh3;
  bias[gid] = bi[r] + bh[r];
}

// Hand-rolled grid barrier: monotonic counter, agent-scope.
__device__ __forceinline__ void gridbar(unsigned* cnt, unsigned target) {
  __syncthreads();
  if (threadIdx.x == 0) {
    __threadfence();
    __hip_atomic_fetch_add(cnt, 1u, __ATOMIC_RELEASE, __HIP_MEMORY_SCOPE_AGENT);
    while (__hip_atomic_load(cnt, __ATOMIC_ACQUIRE, __HIP_MEMORY_SCOPE_AGENT) < target)
      __builtin_amdgcn_s_sleep(1);
    __threadfence();
  }
  __syncthreads();
}

// Persistent fused LSTM: 256 blocks x 256 threads, 1 block/CU.
// Block = (b-tile of 32, j-tile of 8) and processes ALL 3 layers each phase
// (layer l at t = p - l) -> perfectly uniform work per block.
// Wave = (bsub, nsub): 16x16 MFMA subtile; A-frags read directly from global
// (h arrays / embed), B-frags from packed weights; NO barriers in K-loop.
__global__ __launch_bounds__(256) void lstm_fused(
    const float* __restrict__ embed,
    const unsigned short* __restrict__ whi,
    const unsigned short* __restrict__ wlo,
    const float* __restrict__ bias,
    unsigned short* __restrict__ hhi,
    unsigned short* __restrict__ hlo,
    float* __restrict__ h3f,
    const float* __restrict__ fcw, const float* __restrict__ fcb,
    float* __restrict__ out, unsigned* __restrict__ cnt)
{
  const int bid = blockIdx.x;
  // XCD-locality: bid&7 = XCD (round-robin dispatch) owns jt range [xcd*8, xcd*8+8)
  const int xcd = bid & 7;
  const int idx = bid >> 3;           // 0..31
  const int jt  = xcd * 8 + (idx & 7);
  const int bt  = idx >> 3;           // 0..3
  const int j0  = jt * 8;
  const int b0  = bt * 32;
  const int tid = (int)threadIdx.x;
  const int lane = tid & 63;
  const int wave = tid >> 6;
  const int bsub = wave >> 1, nsub = wave & 1;

  __shared__ float pre[2][32][36];    // stride 36: conflict-free write/read
  __shared__ float sbias[3][32];

  if (tid < 96) {
    int l = tid >> 5, n = tid & 31;
    sbias[l][n] = bias[l * 2048 + (n >> 3) * 512 + j0 + (n & 7)];
  }
  // zero h state (ws poisoned; must be deterministic per launch)
  for (int i = bid * 256 + tid; i < 3 * 2 * Bn * Hn; i += NB * 256) { hhi[i] = 0; hlo[i] = 0; }

  float c0 = 0.f, c1 = 0.f, c2 = 0.f;   // cell state for (b0+(tid>>3), j0+(tid&7))
  unsigned bar_t = NB;
  gridbar(cnt, bar_t); bar_t += NB;

  const int arow = b0 + bsub * 16 + (lane & 15);   // b row for A-fragment
  const int kgrp = (lane >> 4) * 8;                // k-offset within 32-chunk
  const int bloc = tid >> 3, jl = tid & 7;         // cell-update mapping

  for (int p = 0; p <= 1024; ++p) {
    const int rp = (p + 1) & 1, wp = p & 1;

#pragma unroll
    for (int l = 0; l < 3; ++l) {
      const int t = p - l;
      if (t < 0 || t > 1022) continue;
      const int NCH = (l == 0) ? 24 : 32;
      const size_t wbase = (l == 0) ? 0u : ((l == 1) ? 1572864u : 3670016u);
      const unsigned short* wh = whi + wbase + ((size_t)(jt * 2 + nsub) * NCH) * 512 + lane * 8;
      const unsigned short* wl = wlo + wbase + ((size_t)(jt * 2 + nsub) * NCH) * 512 + lane * 8;

      f32x4 aHH = {0.f,0.f,0.f,0.f}, aLH = {0.f,0.f,0.f,0.f}, aHL = {0.f,0.f,0.f,0.f};

#pragma unroll
      for (int kc = 0; kc < 32; ++kc) {
        if (l == 0 && kc >= 24) break;
        const int k0 = kc * 32 + kgrp;
        bf16x8 ahi, alo;
        if (l == 0 && k0 < 256) {          // embed (fp32) -> split bf16 in-register
          const float* s = embed + ((size_t)arow * Tn + t) * INn + k0;
          const float4 x0 = *reinterpret_cast<const float4*>(s);
          const float4 x1 = *reinterpret_cast<const float4*>(s + 4);
          float xs[8] = {x0.x, x0.y, x0.z, x0.w, x1.x, x1.y, x1.z, x1.w};
#pragma unroll
          for (int e = 0; e < 8; ++e) {
            unsigned short h = bf_hi(xs[e]);
            ahi[e] = (short)h; alo[e] = (short)bf_hi(xs[e] - bf_f(h));
          }
        } else {
          int srcl, off;
          if (l == 0)           { srcl = 0;     off = k0 - 256; }
          else if (k0 < 512)    { srcl = l - 1; off = k0;       }
          else                  { srcl = l;     off = k0 - 512; }
          const size_t ho = ((size_t)(srcl * 2 + rp) * Bn + arow) * Hn + off;
          ahi = *reinterpret_cast<const bf16x8*>(hhi + ho);
          alo = *reinterpret_cast<const bf16x8*>(hlo + ho);
        }
        const bf16x8 bhi = *reinterpret_cast<const bf16x8*>(wh + (size_t)kc * 512);
        const bf16x8 blo = *reinterpret_cast<const bf16x8*>(wl + (size_t)kc * 512);
        aHH = __builtin_amdgcn_mfma_f32_16x16x32_bf16(ahi, bhi, aHH, 0, 0, 0);
        aLH = __builtin_amdgcn_mfma_f32_16x16x32_bf16(alo, bhi, aLH, 0, 0, 0);
        aHL = __builtin_amdgcn_mfma_f32_16x16x32_bf16(ahi, blo, aHL, 0, 0, 0);
      }

      const int pb = l & 1;               // pre buffer parity (0,1,0) - safe, see sync order
      {
        const int prow = bsub * 16 + ((lane >> 4) << 2);
        const int pc = nsub * 16 + (lane & 15);
#pragma unroll
        for (int r = 0; r < 4; ++r)
          pre[pb][prow + r][pc] = aHH[r] + aLH[r] + aHL[r];
      }
      __syncthreads();
      {
        const float ig = sigm(pre[pb][bloc][jl]       + sbias[l][jl]);
        const float fg = sigm(pre[pb][bloc][8 + jl]   + sbias[l][8 + jl]);
        const float gg = tanhf(pre[pb][bloc][16 + jl] + sbias[l][16 + jl]);
        const float og = sigm(pre[pb][bloc][24 + jl]  + sbias[l][24 + jl]);
        float& c = (l == 0) ? c0 : ((l == 1) ? c1 : c2);
        c = fg * c + ig * gg;
        const float hv = og * tanhf(c);
        const unsigned short hh = bf_hi(hv);
        const size_t ho = ((size_t)(l * 2 + wp) * Bn + (b0 + bloc)) * Hn + (j0 + jl);
        hhi[ho] = hh;
        hlo[ho] = bf_hi(hv - bf_f(hh));
        if (l == 2 && t == 1022)
          h3f[(size_t)(b0 + bloc) * Hn + (j0 + jl)] = hv;
      }
    }
    gridbar(cnt, bar_t); bar_t += NB;
  }

  // FC epilogue: out2[b][o] = h3_final[b,:] . fc_w[o,:] + fc_b[o]
  const int gid = bid * 256 + tid;
  if (gid < Bn * INn) {
    const int b = gid >> 8, o = gid & 255;
    const float* hr = h3f + (size_t)b * Hn;
    const float* wr = fcw + (size_t)o * Hn;
    float acc = fcb[o];
#pragma unroll 4
    for (int k = 0; k < Hn; k += 4) {
      const float4 hv = *reinterpret_cast<const float4*>(hr + k);
      const float4 wv = *reinterpret_cast<const float4*>(wr + k);
      acc = fmaf(hv.x, wv.x, acc); acc = fmaf(hv.y, wv.y, acc);
      acc = fmaf(hv.z, wv.z, acc); acc = fmaf(hv.w, wv.w, acc);
    }
    out[(size_t)Bn * Tn * INn + gid] = acc;
  }
}

extern "C" void kernel_launch(void* const* d_in, const int* in_sizes, int n_in,
                              void* d_out, int out_size, void* d_ws, size_t ws_size,
                              hipStream_t stream) {
  const float* embed = (const float*)d_in[0];
  const float* wih1  = (const float*)d_in[1];
  const float* whh1  = (const float*)d_in[2];
  const float* bih1  = (const float*)d_in[3];
  const float* bhh1  = (const float*)d_in[4];
  const float* wih2  = (const float*)d_in[5];
  const float* whh2  = (const float*)d_in[6];
  const float* bih2  = (const float*)d_in[7];
  const float* bhh2  = (const float*)d_in[8];
  const float* wih3  = (const float*)d_in[9];
  const float* whh3  = (const float*)d_in[10];
  const float* bih3  = (const float*)d_in[11];
  const float* bhh3  = (const float*)d_in[12];
  const float* fcw   = (const float*)d_in[13];
  const float* fcb   = (const float*)d_in[14];
  float* outp = (float*)d_out;

  char* ws = (char*)d_ws;
  unsigned short* whi = (unsigned short*)(ws + WHI_OFF);
  unsigned short* wlo = (unsigned short*)(ws + WLO_OFF);
  float* bias         = (float*)(ws + BIAS_OFF);
  unsigned short* hhi = (unsigned short*)(ws + HHI_OFF);
  unsigned short* hlo = (unsigned short*)(ws + HLO_OFF);
  float* h3f          = (float*)(ws + H3F_OFF);
  unsigned* cnt       = (unsigned*)(ws + CNT_OFF);

  // Output 0: embed passthrough (128 MB d2d)
  hipMemcpyAsync(d_out, d_in[0], (size_t)Bn * Tn * INn * sizeof(float),
                 hipMemcpyDeviceToDevice, stream);
  // barrier counter must start at 0 every launch
  hipMemsetAsync(cnt, 0, 64, stream);

  pack_weights<<<2816, 256, 0, stream>>>(wih1, whh1, wih2, whh2, wih3, whh3, whi, wlo);
  pack_bias<<<24, 256, 0, stream>>>(bih1, bhh1, bih2, bhh2, bih3, bhh3, bias);

  void* args[] = { (void*)&embed, (void*)&whi, (void*)&wlo, (void*)&bias,
                   (void*)&hhi, (void*)&hlo, (void*)&h3f,
                   (void*)&fcw, (void*)&fcb, (void*)&outp, (void*)&cnt };
  dim3 grid(NB), block(256);
  hipLaunchCooperativeKernel((const void*)lstm_fused, grid, block, args, 0, stream);
}

// Round 4
// 54841.150 us; speedup vs baseline: 4.1692x; 1.1337x over previous
//
#include <hip/hip_runtime.h>

#define Bn 128
#define Tn 1024
#define INn 256
#define Hn 512
#define NB 256   // persistent blocks (1 per CU), 512 threads each

typedef short bf16x8 __attribute__((ext_vector_type(8)));
typedef float f32x4 __attribute__((ext_vector_type(4)));

// ---- ws layout (bytes) ----
#define WHI_OFF  0u
#define WLO_OFF  11534336u
#define BIAS_OFF 23068672u
#define HH_OFF   23093248u
#define HM_OFF   23879680u
#define HL_OFF   24666112u
#define H3F_OFF  25452544u
#define CNT_OFF  25714688u   // 2KB barrier area

__device__ __forceinline__ float sigm(float x) { return 1.0f / (1.0f + __expf(-x)); }
__device__ __forceinline__ unsigned short bf_hi(float x) {
  unsigned u = __builtin_bit_cast(unsigned, x);
  return (unsigned short)(u >> 16);
}
__device__ __forceinline__ float bf_f(unsigned short h) {
  unsigned u = ((unsigned)h) << 16;
  return __builtin_bit_cast(float, u);
}

// Pack fp32 weights into MFMA-fragment-ordered bf16 hi/lo arrays (layout as r3).
// dst elem offset = layer_base + (((jt*2+ns)*NCH + kc)*64 + lane)*8
// col n = ns*16+(lane&15) -> gate row r = (n>>3)*512 + jt*8 + (n&7),
// k0 = kc*32 + (lane>>4)*8 over concat [x ; h]  (same (lane,e)->k map as A-frags).
__global__ void pack_weights(const float* __restrict__ wih1, const float* __restrict__ whh1,
                             const float* __restrict__ wih2, const float* __restrict__ whh2,
                             const float* __restrict__ wih3, const float* __restrict__ whh3,
                             unsigned short* __restrict__ whi, unsigned short* __restrict__ wlo) {
  int gid = blockIdx.x * 256 + threadIdx.x;
  int rem, NCH, kih; size_t base; const float *wih, *whh;
  if (gid < 196608)      { rem = gid;          base = 0;       NCH = 24; kih = 256; wih = wih1; whh = whh1; }
  else if (gid < 458752) { rem = gid - 196608; base = 1572864; NCH = 32; kih = 512; wih = wih2; whh = whh2; }
  else if (gid < 720896) { rem = gid - 458752; base = 3670016; NCH = 32; kih = 512; wih = wih3; whh = whh3; }
  else return;
  const int lane = rem & 63; rem >>= 6;
  const int kc = rem % NCH; rem /= NCH;
  const int ns = rem & 1;
  const int jt = rem >> 1;
  const int n = ns * 16 + (lane & 15);
  const int g = n >> 3, jl = n & 7;
  const int r = g * 512 + jt * 8 + jl;
  const int k0 = kc * 32 + (lane >> 4) * 8;
  const float* src = (k0 < kih) ? (wih + (size_t)r * kih + k0)
                                : (whh + (size_t)r * 512 + (k0 - kih));
  size_t dst = base + ((((size_t)jt * 2 + ns) * NCH + kc) * 64 + lane) * 8;
#pragma unroll
  for (int e = 0; e < 8; ++e) {
    float w = src[e];
    unsigned short h = bf_hi(w);
    whi[dst + e] = h;
    wlo[dst + e] = bf_hi(w - bf_f(h));
  }
}

__global__ void pack_bias(const float* __restrict__ bi1, const float* __restrict__ bh1,
                          const float* __restrict__ bi2, const float* __restrict__ bh2,
                          const float* __restrict__ bi3, const float* __restrict__ bh3,
                          float* __restrict__ bias) {
  int gid = blockIdx.x * 256 + threadIdx.x;
  if (gid >= 6144) return;
  int l = gid >> 11, r = gid & 2047;
  const float* bi = (l == 0) ? bi1 : (l == 1) ? bi2 : bi3;
  const float* bh = (l == 0) ? bh1 : (l == 1) ? bh2 : bh3;
  bias[gid] = bi[r] + bh[r];
}

// Two-level flag barrier. bar: [x*32] per-XCD ctr (x=0..7, 128B apart),
// [256] root, [288] epoch. Monotonic idx (1-based). Pollers use RELAXED on
// a line that is never RMW'd, one ACQUIRE at the end.
__device__ __forceinline__ void gridbar(unsigned* bar, unsigned idx, int xcd) {
  __syncthreads();
  if (threadIdx.x == 0) {
    unsigned* xc   = bar + xcd * 32;
    unsigned* root = bar + 256;
    unsigned* ep   = bar + 288;
    unsigned o = __hip_atomic_fetch_add(xc, 1u, __ATOMIC_ACQ_REL, __HIP_MEMORY_SCOPE_AGENT);
    if (o == idx * 32u - 1u) {
      unsigned r = __hip_atomic_fetch_add(root, 1u, __ATOMIC_ACQ_REL, __HIP_MEMORY_SCOPE_AGENT);
      if (r == idx * 8u - 1u)
        __hip_atomic_store(ep, idx, __ATOMIC_RELEASE, __HIP_MEMORY_SCOPE_AGENT);
    }
    while (__hip_atomic_load(ep, __ATOMIC_RELAXED, __HIP_MEMORY_SCOPE_AGENT) < idx)
      __builtin_amdgcn_s_sleep(1);
    (void)__hip_atomic_load(ep, __ATOMIC_ACQUIRE, __HIP_MEMORY_SCOPE_AGENT);
  }
  __syncthreads();
}

// Persistent fused LSTM: 256 blocks x 512 threads (8 waves/CU, 2/SIMD).
// Block = (b-tile 32, j-tile 8), all 3 layers each phase (layer l at t=p-l).
// Wave w: bsub=w&1 (16 b-rows), nsub=(w>>1)&1 (16 gate-cols), kq=w>>2 (K half).
// A = 3-split bf16 (hi/mid/lo), B = 2-split; 5 MFMAs -> ~2^-24 product error.
__global__ __launch_bounds__(512, 2) void lstm_fused(
    const float* __restrict__ embed,
    const unsigned short* __restrict__ whi,
    const unsigned short* __restrict__ wlo,
    const float* __restrict__ bias,
    unsigned short* __restrict__ hh,
    unsigned short* __restrict__ hm,
    unsigned short* __restrict__ hl,
    float* __restrict__ h3f,
    const float* __restrict__ fcw, const float* __restrict__ fcb,
    float* __restrict__ out, unsigned* __restrict__ bar)
{
  const int bid = blockIdx.x;
  const int xcd = bid & 7;
  const int idx = bid >> 3;           // 0..31
  const int jt  = xcd * 8 + (idx & 7);
  const int bt  = idx >> 3;           // 0..3
  const int j0  = jt * 8;
  const int b0  = bt * 32;
  const int tid = (int)threadIdx.x;
  const int lane = tid & 63;
  const int w = tid >> 6;
  const int bsub = w & 1, nsub = (w >> 1) & 1, kq = w >> 2;

  __shared__ float pre[2][2][32][36];   // [parity][kq][brow][gatecol]
  __shared__ float sbias[3][32];

  if (tid < 96) {
    int l = tid >> 5, n = tid & 31;
    sbias[l][n] = bias[l * 2048 + (n >> 3) * 512 + j0 + (n & 7)];
  }
  // zero h state (ws poisoned; deterministic per launch)
  for (int i = bid * 512 + tid; i < 3 * 2 * Bn * Hn; i += NB * 512) {
    hh[i] = 0; hm[i] = 0; hl[i] = 0;
  }

  float c0 = 0.f, c1 = 0.f, c2 = 0.f;   // cell state for (b0+(tid>>3), j0+(tid&7)), tid<256
  unsigned bidx = 1;
  gridbar(bar, bidx++, xcd);

  const int arow = b0 + bsub * 16 + (lane & 15);   // A-frag b row
  const int kgrp = (lane >> 4) * 8;                // k-offset in 32-chunk
  const int bloc = (tid >> 3) & 31, jl = tid & 7;  // cell-update mapping (tid<256)

  for (int p = 0; p <= 1024; ++p) {
    const int rp = (p + 1) & 1, wp = p & 1;

#pragma unroll
    for (int l = 0; l < 3; ++l) {
      const int t = p - l;
      if (t < 0 || t > 1022) continue;
      const int NCH = (l == 0) ? 24 : 32;
      const int half = NCH >> 1;
      const size_t wbase = (l == 0) ? 0u : ((l == 1) ? 1572864u : 3670016u);
      const unsigned short* wh = whi + wbase + ((size_t)(jt * 2 + nsub) * NCH) * 512 + lane * 8;
      const unsigned short* wl = wlo + wbase + ((size_t)(jt * 2 + nsub) * NCH) * 512 + lane * 8;

      f32x4 accA = {0.f,0.f,0.f,0.f}, accB = {0.f,0.f,0.f,0.f};
      const int kc0 = kq * half;

#pragma unroll
      for (int i = 0; i < 16; ++i) {
        if (i >= half) break;                      // 12 or 16, compile-time per l
        const int kc = kc0 + i;
        const int k0 = kc * 32 + kgrp;
        bf16x8 aH, aM, aL;
        if (l == 0 && k0 < 256) {                  // embed fp32 -> 3-split in-register
          const float* s = embed + ((size_t)arow * Tn + t) * INn + k0;
          const float4 x0 = *reinterpret_cast<const float4*>(s);
          const float4 x1 = *reinterpret_cast<const float4*>(s + 4);
          float xs[8] = {x0.x, x0.y, x0.z, x0.w, x1.x, x1.y, x1.z, x1.w};
#pragma unroll
          for (int e = 0; e < 8; ++e) {
            unsigned short h1 = bf_hi(xs[e]);
            float r1 = xs[e] - bf_f(h1);
            unsigned short m1 = bf_hi(r1);
            aH[e] = (short)h1; aM[e] = (short)m1;
            aL[e] = (short)bf_hi(r1 - bf_f(m1));
          }
        } else {
          int srcl, off;
          if (l == 0)           { srcl = 0;     off = k0 - 256; }
          else if (k0 < 512)    { srcl = l - 1; off = k0;       }
          else                  { srcl = l;     off = k0 - 512; }
          const size_t ho = ((size_t)(srcl * 2 + rp) * Bn + arow) * Hn + off;
          aH = *reinterpret_cast<const bf16x8*>(hh + ho);
          aM = *reinterpret_cast<const bf16x8*>(hm + ho);
          aL = *reinterpret_cast<const bf16x8*>(hl + ho);
        }
        const bf16x8 bH = *reinterpret_cast<const bf16x8*>(wh + (size_t)kc * 512);
        const bf16x8 bL = *reinterpret_cast<const bf16x8*>(wl + (size_t)kc * 512);
        accA = __builtin_amdgcn_mfma_f32_16x16x32_bf16(aH, bH, accA, 0, 0, 0);
        accA = __builtin_amdgcn_mfma_f32_16x16x32_bf16(aM, bH, accA, 0, 0, 0);
        accA = __builtin_amdgcn_mfma_f32_16x16x32_bf16(aL, bH, accA, 0, 0, 0);
        accB = __builtin_amdgcn_mfma_f32_16x16x32_bf16(aH, bL, accB, 0, 0, 0);
        accB = __builtin_amdgcn_mfma_f32_16x16x32_bf16(aM, bL, accB, 0, 0, 0);
      }

      const int pb = l & 1;  // parity trick: l2's reuse of plane 0 is fenced by l1's syncthreads
      {
        const int prow = bsub * 16 + ((lane >> 4) << 2);
        const int pc = nsub * 16 + (lane & 15);
#pragma unroll
        for (int r = 0; r < 4; ++r)
          pre[pb][kq][prow + r][pc] = accA[r] + accB[r];
      }
      __syncthreads();
      if (tid < 256) {
        const float g0 = pre[pb][0][bloc][jl]      + pre[pb][1][bloc][jl]      + sbias[l][jl];
        const float g1 = pre[pb][0][bloc][8 + jl]  + pre[pb][1][bloc][8 + jl]  + sbias[l][8 + jl];
        const float g2 = pre[pb][0][bloc][16 + jl] + pre[pb][1][bloc][16 + jl] + sbias[l][16 + jl];
        const float g3 = pre[pb][0][bloc][24 + jl] + pre[pb][1][bloc][24 + jl] + sbias[l][24 + jl];
        const float ig = sigm(g0), fg = sigm(g1), gg = tanhf(g2), og = sigm(g3);
        float& c = (l == 0) ? c0 : ((l == 1) ? c1 : c2);
        c = fg * c + ig * gg;
        const float hv = og * tanhf(c);
        const unsigned short h1 = bf_hi(hv);
        const float r1 = hv - bf_f(h1);
        const unsigned short m1 = bf_hi(r1);
        const size_t ho = ((size_t)(l * 2 + wp) * Bn + (b0 + bloc)) * Hn + (j0 + jl);
        hh[ho] = h1;
        hm[ho] = m1;
        hl[ho] = bf_hi(r1 - bf_f(m1));
        if (l == 2 && t == 1022)
          h3f[(size_t)(b0 + bloc) * Hn + (j0 + jl)] = hv;
      }
    }
    gridbar(bar, bidx++, xcd);
  }

  // FC epilogue: out2[b][o] = h3_final[b,:] . fc_w[o,:] + fc_b[o]
  const int gid = bid * 512 + tid;
  if (gid < Bn * INn) {
    const int b = gid >> 8, o = gid & 255;
    const float* hr = h3f + (size_t)b * Hn;
    const float* wr = fcw + (size_t)o * Hn;
    float acc = fcb[o];
#pragma unroll 4
    for (int k = 0; k < Hn; k += 4) {
      const float4 hv = *reinterpret_cast<const float4*>(hr + k);
      const float4 wv = *reinterpret_cast<const float4*>(wr + k);
      acc = fmaf(hv.x, wv.x, acc); acc = fmaf(hv.y, wv.y, acc);
      acc = fmaf(hv.z, wv.z, acc); acc = fmaf(hv.w, wv.w, acc);
    }
    out[(size_t)Bn * Tn * INn + gid] = acc;
  }
}

extern "C" void kernel_launch(void* const* d_in, const int* in_sizes, int n_in,
                              void* d_out, int out_size, void* d_ws, size_t ws_size,
                              hipStream_t stream) {
  const float* embed = (const float*)d_in[0];
  const float* wih1  = (const float*)d_in[1];
  const float* whh1  = (const float*)d_in[2];
  const float* bih1  = (const float*)d_in[3];
  const float* bhh1  = (const float*)d_in[4];
  const float* wih2  = (const float*)d_in[5];
  const float* whh2  = (const float*)d_in[6];
  const float* bih2  = (const float*)d_in[7];
  const float* bhh2  = (const float*)d_in[8];
  const float* wih3  = (const float*)d_in[9];
  const float* whh3  = (const float*)d_in[10];
  const float* bih3  = (const float*)d_in[11];
  const float* bhh3  = (const float*)d_in[12];
  const float* fcw   = (const float*)d_in[13];
  const float* fcb   = (const float*)d_in[14];
  float* outp = (float*)d_out;

  char* ws = (char*)d_ws;
  unsigned short* whi = (unsigned short*)(ws + WHI_OFF);
  unsigned short* wlo = (unsigned short*)(ws + WLO_OFF);
  float* bias         = (float*)(ws + BIAS_OFF);
  unsigned short* hh  = (unsigned short*)(ws + HH_OFF);
  unsigned short* hm  = (unsigned short*)(ws + HM_OFF);
  unsigned short* hl  = (unsigned short*)(ws + HL_OFF);
  float* h3f          = (float*)(ws + H3F_OFF);
  unsigned* bar       = (unsigned*)(ws + CNT_OFF);

  // Output 0: embed passthrough (128 MB d2d)
  hipMemcpyAsync(d_out, d_in[0], (size_t)Bn * Tn * INn * sizeof(float),
                 hipMemcpyDeviceToDevice, stream);
  // barrier counters must start at 0 every launch
  hipMemsetAsync(bar, 0, 2048, stream);

  pack_weights<<<2816, 256, 0, stream>>>(wih1, whh1, wih2, whh2, wih3, whh3, whi, wlo);
  pack_bias<<<24, 256, 0, stream>>>(bih1, bhh1, bih2, bhh2, bih3, bhh3, bias);

  void* args[] = { (void*)&embed, (void*)&whi, (void*)&wlo, (void*)&bias,
                   (void*)&hh, (void*)&hm, (void*)&hl, (void*)&h3f,
                   (void*)&fcw, (void*)&fcb, (void*)&outp, (void*)&bar };
  dim3 grid(NB), block(512);
  hipLaunchCooperativeKernel((const void*)lstm_fused, grid, block, args, 0, stream);
}